// Round 1
// baseline (563.114 us; speedup 1.0000x reference)
//
#include <hip/hip_runtime.h>
#include <hip/hip_bf16.h>

// Problem constants (fixed by the reference):
#define E_EDGES 640000
#define DIM     128
#define N_NODES 40000

typedef __bf16 bf16x8 __attribute__((ext_vector_type(8)));
typedef float  floatx4 __attribute__((ext_vector_type(4)));

// prep: (a) init out to -inf (0xFF800000) so empty segments match jax segment_max
//       and atomicMax-on-int works for post-relu (>=0) values,
//       (b) swizzle W (fp32 [128][128], W[f][d]) into bf16 B-fragment lane order:
//       Wsw[((nb*4+kb)*64 + lane)*8 + j] = W[nb*16 + (lane&15)][kb*32 + (lane>>4)*8 + j]
__global__ void prep_kernel(const float* __restrict__ W,
                            __bf16* __restrict__ Wsw,
                            int* __restrict__ out_i) {
    int tid = blockIdx.x * blockDim.x + threadIdx.x;
    if (tid < N_NODES * DIM) out_i[tid] = 0xFF800000;  // -inf
    if (tid < 2048) {
        int lane = tid & 63;
        int kb   = (tid >> 6) & 3;
        int nb   = tid >> 8;
        int f    = nb * 16 + (lane & 15);
        int k0   = kb * 32 + ((lane >> 4) & 3) * 8;
        const float* wrow = W + f * DIM + k0;
        __bf16* o = Wsw + tid * 8;
#pragma unroll
        for (int j = 0; j < 8; ++j) o[j] = (__bf16)wrow[j];
    }
}

// One wave computes msg[16 edges][128 features] = relu(src@W^T + b) with
// 4 kblocks x 8 nblocks of mfma_f32_16x16x32_bf16, then scatters via atomicMax.
// A-frag:  A[m=lane&15][k=quad*8+j]      (loaded straight from global, coalesced rows)
// B-frag:  B[k=quad*8+j][n=lane&15]      (pre-swizzled: lane-consecutive 16B loads)
// C/D:     col=lane&15, row=quad*4+reg
__global__ __launch_bounds__(256)
void gemm_atomic_kernel(const float* __restrict__ src,
                        const __bf16* __restrict__ Wsw,
                        const float* __restrict__ bias,
                        const int* __restrict__ dst,
                        int* __restrict__ out_i) {
    const int lane = threadIdx.x & 63;
    const int wave = threadIdx.x >> 6;
    const int q    = lane >> 4;
    const int n    = lane & 15;
    const int eb   = blockIdx.x * 64 + wave * 16;   // 16 edges per wave

    floatx4 acc[8];
#pragma unroll
    for (int nb = 0; nb < 8; ++nb) acc[nb] = (floatx4)(0.0f);

    const float* arow = src + (size_t)(eb + n) * DIM + q * 8;
    const bf16x8* Wf = (const bf16x8*)Wsw;

#pragma unroll
    for (int kb = 0; kb < 4; ++kb) {
        float4 a0 = *(const float4*)(arow + kb * 32);
        float4 a1 = *(const float4*)(arow + kb * 32 + 4);
        bf16x8 af;
        af[0] = (__bf16)a0.x; af[1] = (__bf16)a0.y;
        af[2] = (__bf16)a0.z; af[3] = (__bf16)a0.w;
        af[4] = (__bf16)a1.x; af[5] = (__bf16)a1.y;
        af[6] = (__bf16)a1.z; af[7] = (__bf16)a1.w;
#pragma unroll
        for (int nb = 0; nb < 8; ++nb) {
            bf16x8 bf = Wf[(nb * 4 + kb) * 64 + lane];
            acc[nb] = __builtin_amdgcn_mfma_f32_16x16x32_bf16(af, bf, acc[nb], 0, 0, 0);
        }
    }

    // epilogue: relu(acc + bias) -> atomicMax scatter (int-compare valid for >=0 floats)
    int nodes[4];
#pragma unroll
    for (int r = 0; r < 4; ++r) nodes[r] = dst[eb + q * 4 + r];
#pragma unroll
    for (int nb = 0; nb < 8; ++nb) {
        const int col = nb * 16 + n;
        const float bv = bias[col];
#pragma unroll
        for (int r = 0; r < 4; ++r) {
            float v = acc[nb][r] + bv;
            v = v > 0.0f ? v : 0.0f;
            atomicMax(out_i + (size_t)nodes[r] * DIM + col, __float_as_int(v));
        }
    }
}

extern "C" void kernel_launch(void* const* d_in, const int* in_sizes, int n_in,
                              void* d_out, int out_size, void* d_ws, size_t ws_size,
                              hipStream_t stream) {
    const float* src  = (const float*)d_in[0];
    const float* W    = (const float*)d_in[1];
    const float* bias = (const float*)d_in[2];
    const int*   dst  = (const int*)d_in[3];
    // d_in[4] = n_nodes (scalar) — compile-time constant here.

    __bf16* Wsw  = (__bf16*)d_ws;         // 32 KB swizzled bf16 W
    int*    outi = (int*)d_out;

    // init out (-inf) + swizzle W; covers N_NODES*DIM = 5.12M elements
    prep_kernel<<<(N_NODES * DIM + 255) / 256, 256, 0, stream>>>(W, Wsw, outi);
    // 64 edges per block (4 waves x 16 edges), E/64 = 10000 blocks
    gemm_atomic_kernel<<<E_EDGES / 64, 256, 0, stream>>>(src, Wsw, bias, dst, outi);
}